// Round 6
// baseline (18.907 us; speedup 1.0000x reference)
//
#include <hip/hip_runtime.h>
#include <math.h>

#define BLK   1024
#define MAXF  512          // max frequency bins supported (F = 201 here)
#define NW    (BLK / 64)   // 16 waves per block
// ws layout (unsigned): [0] completion counter, [64 .. 64+MAXF) psd bit-patterns

// fast (a mod fs); exact for a < 2^24 (all uses here satisfy that: f*4*tid <= 240*4092)
__device__ __forceinline__ unsigned umod_fast(unsigned a, unsigned fs, float inv_fs) {
    unsigned q = (unsigned)((float)a * inv_fs);
    int r = (int)a - (int)(q * fs);
    if (r < 0) r += (int)fs;
    if (r < 0) r += (int)fs;
    if (r >= (int)fs) r -= (int)fs;
    if (r >= (int)fs) r -= (int)fs;
    return (unsigned)r;
}

// One fused kernel. Each block owns whole frequencies (SPLIT=1): full-N polyphase-4
// projection -> block reduce -> psd published via device-scope atomicExch (coherent
// RMW, no threadfence). Completion counter via atomicAdd, ordered by s_waitcnt
// vmcnt(0) (wave-local wait, NOT an L2 writeback like R3's fence storm). The block
// that completes the last frequency reads all psd values back with atomicOr(.,0)
// (coherent RMW reads) in fixed order -> deterministic final sum -> loss.
__global__ void __launch_bounds__(BLK) extractor_kernel(
    const float* __restrict__ x, int N,
    const int* __restrict__ p_ftrue,
    const int* __restrict__ p_fs,
    const int* __restrict__ p_delta,
    const int* __restrict__ p_fmin,
    const int* __restrict__ p_fmax,
    unsigned* __restrict__ wsu,
    float* __restrict__ out)
{
    const unsigned fs   = (unsigned)*p_fs;
    const int      fmin = *p_fmin;
    const int      fmax = *p_fmax;
    int F = fmax - fmin + 1;
    if (F > MAXF) F = MAXF;
    const float inv_fs = 1.0f / (float)fs;

    unsigned* counter = wsu;
    unsigned* psd_u   = wsu + 64;

    __shared__ float    red[2 * NW];
    __shared__ unsigned s_last;

    const int tid  = threadIdx.x;
    const int lane = tid & 63;
    const int wid  = tid >> 6;

    for (int j = blockIdx.x; j < F; j += gridDim.x) {
        const unsigned f = (unsigned)(fmin + j);

        // --- exact integer angles (products < 2^24 -> float-exact umod) ---
        const unsigned k0 = umod_fast(f * (unsigned)(4 * tid), fs, inv_fs); // elem 4*tid
        const unsigned k4 = umod_fast(f * (unsigned)(4 * BLK), fs, inv_fs); // stride 4*BLK
        unsigned k8 = k4 + k4; if (k8 >= fs) k8 -= fs;                      // stride 8*BLK
        const unsigned kf = umod_fast(f, fs, inv_fs);                       // stride 1

        // phasors + rotation constants (revolution-argument HW trans, zero range red.)
        float cA = __builtin_amdgcn_cosf((float)k0 * inv_fs);
        float sA = __builtin_amdgcn_sinf((float)k0 * inv_fs);
        const float C4 = __builtin_amdgcn_cosf((float)k4 * inv_fs);
        const float S4 = __builtin_amdgcn_sinf((float)k4 * inv_fs);
        float cB = fmaf(cA, C4, -(sA * S4));   // phasor at 4*tid + 4*BLK
        float sB = fmaf(sA, C4,  (cA * S4));
        const float C8 = __builtin_amdgcn_cosf((float)k8 * inv_fs);
        const float S8 = __builtin_amdgcn_sinf((float)k8 * inv_fs);

        // 4 polyphase complex accumulators (phases p=0..3 within each float4)
        float a0r = 0.f, a0i = 0.f, a1r = 0.f, a1i = 0.f;
        float a2r = 0.f, a2i = 0.f, a3r = 0.f, a3i = 0.f;

        int b = 4 * tid;
        for (; b + 4 * BLK + 4 <= N; b += 8 * BLK) {   // ~12 iterations
            float4 xa = *reinterpret_cast<const float4*>(x + b);
            float4 xb = *reinterpret_cast<const float4*>(x + b + 4 * BLK);
            a0r = fmaf(xa.x, cA, a0r); a0i = fmaf(xa.x, sA, a0i);
            a1r = fmaf(xa.y, cA, a1r); a1i = fmaf(xa.y, sA, a1i);
            a2r = fmaf(xa.z, cA, a2r); a2i = fmaf(xa.z, sA, a2i);
            a3r = fmaf(xa.w, cA, a3r); a3i = fmaf(xa.w, sA, a3i);
            a0r = fmaf(xb.x, cB, a0r); a0i = fmaf(xb.x, sB, a0i);
            a1r = fmaf(xb.y, cB, a1r); a1i = fmaf(xb.y, sB, a1i);
            a2r = fmaf(xb.z, cB, a2r); a2i = fmaf(xb.z, sB, a2i);
            a3r = fmaf(xb.w, cB, a3r); a3i = fmaf(xb.w, sB, a3i);
            float cn = fmaf(cA, C8, -(sA * S8));
            float sn = fmaf(sA, C8,  (cA * S8));
            cA = cn; sA = sn;
            cn = fmaf(cB, C8, -(sB * S8));
            sn = fmaf(sB, C8,  (cB * S8));
            cB = cn; sB = sn;
        }
        #pragma unroll
        for (int p = 0; p < 4; ++p) {                  // guarded tail, A position
            int idx = b + p;
            if (idx < N) {
                float xv = x[idx];
                if (p == 0) { a0r = fmaf(xv, cA, a0r); a0i = fmaf(xv, sA, a0i); }
                if (p == 1) { a1r = fmaf(xv, cA, a1r); a1i = fmaf(xv, sA, a1i); }
                if (p == 2) { a2r = fmaf(xv, cA, a2r); a2i = fmaf(xv, sA, a2i); }
                if (p == 3) { a3r = fmaf(xv, cA, a3r); a3i = fmaf(xv, sA, a3i); }
            }
        }
        #pragma unroll
        for (int p = 0; p < 4; ++p) {                  // guarded tail, B position
            int idx = b + 4 * BLK + p;
            if (idx < N) {
                float xv = x[idx];
                if (p == 0) { a0r = fmaf(xv, cB, a0r); a0i = fmaf(xv, sB, a0i); }
                if (p == 1) { a1r = fmaf(xv, cB, a1r); a1i = fmaf(xv, sB, a1i); }
                if (p == 2) { a2r = fmaf(xv, cB, a2r); a2i = fmaf(xv, sB, a2i); }
                if (p == 3) { a3r = fmaf(xv, cB, a3r); a3i = fmaf(xv, sB, a3i); }
            }
        }

        // twiddle combine: sum = A0 + R A1 + R^2 A2 + R^3 A3, R = e^{i 2pi f/fs}
        const float c1 = __builtin_amdgcn_cosf((float)kf * inv_fs);
        const float s1 = __builtin_amdgcn_sinf((float)kf * inv_fs);
        const float c2 = fmaf(c1, c1, -(s1 * s1));
        const float s2 = 2.0f * c1 * s1;
        const float c3 = fmaf(c2, c1, -(s2 * s1));
        const float s3 = fmaf(s2, c1,  (c2 * s1));
        float arS = a0r, aiS = a0i;
        arS = fmaf(c1, a1r, arS); arS = fmaf(-s1, a1i, arS);
        aiS = fmaf(c1, a1i, aiS); aiS = fmaf( s1, a1r, aiS);
        arS = fmaf(c2, a2r, arS); arS = fmaf(-s2, a2i, arS);
        aiS = fmaf(c2, a2i, aiS); aiS = fmaf( s2, a2r, aiS);
        arS = fmaf(c3, a3r, arS); arS = fmaf(-s3, a3i, arS);
        aiS = fmaf(c3, a3i, aiS); aiS = fmaf( s3, a3r, aiS);

        // wave butterfly + block reduce (16 waves)
        #pragma unroll
        for (int o = 32; o > 0; o >>= 1) {
            arS += __shfl_down(arS, o, 64);
            aiS += __shfl_down(aiS, o, 64);
        }
        if (lane == 0) { red[wid * 2] = arS; red[wid * 2 + 1] = aiS; }
        __syncthreads();
        if (tid == 0) {
            float r = 0.f, m = 0.f;
            #pragma unroll
            for (int u = 0; u < NW; ++u) { r += red[u * 2]; m += red[u * 2 + 1]; }
            float psd = r * r + m * m;
            // publish psd at device coherence point (RMW atomic, no fence)
            unsigned oldx = atomicExch(&psd_u[j], __float_as_uint(psd));
            asm volatile("" :: "v"(oldx));                     // keep returning form
            asm volatile("s_waitcnt vmcnt(0)" ::: "memory");   // exch complete first
            unsigned oldc = atomicAdd(counter, 1u);
            s_last = (oldc + 1u == (unsigned)F) ? 1u : 0u;
        }
        __syncthreads();

        if (s_last) {   // block-uniform: this block completed the final frequency
            const int ftrue = *p_ftrue;
            const int delta = *p_delta;
            float t1 = 0.f, t2 = 0.f;
            for (int q = tid; q < F; q += BLK) {       // fixed order -> deterministic
                float psd = __uint_as_float(atomicOr(&psd_u[q], 0u));  // coherent read
                int   fq  = fmin + q;
                bool wanted = (fq >= ftrue - delta) && (fq <= ftrue + delta);
                if (wanted) t1 += psd; else t2 += psd;
            }
            #pragma unroll
            for (int o = 32; o > 0; o >>= 1) {
                t1 += __shfl_down(t1, o, 64);
                t2 += __shfl_down(t2, o, 64);
            }
            if (lane == 0) { red[wid * 2] = t1; red[wid * 2 + 1] = t2; }
            __syncthreads();
            if (tid == 0) {
                float a = 0.f, bb = 0.f;
                #pragma unroll
                for (int u = 0; u < NW; ++u) { a += red[u * 2]; bb += red[u * 2 + 1]; }
                out[0] = -10.0f * log10f(a / bb);
            }
        }
        __syncthreads();  // protect red[] before next grid-stride iteration
    }
}

extern "C" void kernel_launch(void* const* d_in, const int* in_sizes, int n_in,
                              void* d_out, int out_size, void* d_ws, size_t ws_size,
                              hipStream_t stream) {
    const float* x       = (const float*)d_in[0];
    const int*   p_ftrue = (const int*)d_in[1];
    const int*   p_fs    = (const int*)d_in[2];
    const int*   p_delta = (const int*)d_in[3];
    const int*   p_fmin  = (const int*)d_in[4];
    const int*   p_fmax  = (const int*)d_in[5];
    float*       out     = (float*)d_out;
    unsigned*    wsu     = (unsigned*)d_ws;
    const int N = in_sizes[0];

    // completion counter must be 0 every call (ws poisoned once, never re-poisoned)
    hipMemsetAsync(d_ws, 0, sizeof(unsigned), stream);
    // F known only on device; 256 grid-strided blocks of 1024 cover F <= MAXF
    // (F=201 -> 201 active blocks, 16 waves each, one per CU).
    extractor_kernel<<<256, BLK, 0, stream>>>(
        x, N, p_ftrue, p_fs, p_delta, p_fmin, p_fmax, wsu, out);
}

// Round 7
// 14.635 us; speedup vs baseline: 1.2919x; 1.2919x over previous
//
#include <hip/hip_runtime.h>
#include <math.h>

#define BLK   256
#define MAXF  256     // max frequency bins supported (F = 201 here)
#define SPLIT 16      // chunks per frequency-group
#define FPB   4       // frequencies per block (shared x reads -> L2 traffic / FPB)
// ws layout (floats): [0 .. MAXF*SPLIT) re partials, [MAXF*SPLIT .. 2*MAXF*SPLIT) im = 32 KB

// fast (a mod fs); exact for a < 2^24 (uses: f*4*tid <= 240*1020, f*4*BLK, f itself)
__device__ __forceinline__ unsigned umod_fast(unsigned a, unsigned fs, float inv_fs) {
    unsigned q = (unsigned)((float)a * inv_fs);
    int r = (int)a - (int)(q * fs);
    if (r < 0) r += (int)fs;
    if (r < 0) r += (int)fs;
    if (r >= (int)fs) r -= (int)fs;
    if (r >= (int)fs) r -= (int)fs;
    return (unsigned)r;
}

// Kernel 1: per-(freq-group, chunk) partial DFT projection, polyphase-4, FPB freqs
// per block. Each float4 pair is loaded ONCE and accumulated into FPB frequencies
// (L2 traffic / FPB). Exact integer angles at chain heads: k = (f*i) mod fs;
// rev = k/fs in [0,1) feeds v_sin/cos_f32 (revolution-argument, no range reduction).
// Inner cost: 3 VALU ops/element/freq, 2 dwordx4 loads / (8 elements * FPB freqs).
__global__ void __launch_bounds__(BLK) dft_proj_kernel(
    const float* __restrict__ x, int N,
    const int* __restrict__ p_fs,
    const int* __restrict__ p_fmin,
    const int* __restrict__ p_fmax,
    float* __restrict__ ws)
{
    const unsigned fs   = (unsigned)*p_fs;
    const int      fmin = *p_fmin;
    const int      fmax = *p_fmax;
    int F = fmax - fmin + 1;
    if (F > MAXF) F = MAXF;
    const float inv_fs = 1.0f / (float)fs;

    int Nc = (N + SPLIT - 1) / SPLIT;
    Nc = (Nc + 3) & ~3;                        // multiple of 4 -> float4-aligned chunks
    const int ngrp = (F + FPB - 1) / FPB;
    const int W    = ngrp * SPLIT;

    float* re = ws;
    float* im = ws + MAXF * SPLIT;

    __shared__ float red[FPB * 8];             // [g][wave][re,im], 4 waves

    const int tid  = threadIdx.x;
    const int lane = tid & 63;
    const int wid  = tid >> 6;

    for (int w = blockIdx.x; w < W; w += gridDim.x) {
        const int gi    = w >> 4;              // SPLIT == 16
        const int chunk = w & (SPLIT - 1);
        const int j0    = gi * FPB;
        const int cs    = chunk * Nc;
        const int iend  = min(N, cs + Nc);

        float cA[FPB], sA[FPB], cB[FPB], sB[FPB], C8[FPB], S8[FPB];
        float c1[FPB], s1[FPB];
        float a0r[FPB], a0i[FPB], a1r[FPB], a1i[FPB];
        float a2r[FPB], a2i[FPB], a3r[FPB], a3i[FPB];

        #pragma unroll
        for (int g = 0; g < FPB; ++g) {
            int jg = j0 + g; if (jg >= F) jg = F - 1;          // clamp (write-guarded)
            const unsigned f = (unsigned)(fmin + jg);
            // exact integer angles
            const unsigned kb = (unsigned)(((unsigned long long)f * (unsigned)cs) % fs);
            unsigned pt = umod_fast(f * (unsigned)(4 * tid), fs, inv_fs);
            unsigned k0 = kb + pt; if (k0 >= fs) k0 -= fs;
            const unsigned k4 = umod_fast(f * (unsigned)(4 * BLK), fs, inv_fs);
            unsigned k8 = k4 + k4; if (k8 >= fs) k8 -= fs;
            const unsigned kf = umod_fast(f, fs, inv_fs);
            // phasors + rotation constants (8 trans ops per freq)
            cA[g] = __builtin_amdgcn_cosf((float)k0 * inv_fs);
            sA[g] = __builtin_amdgcn_sinf((float)k0 * inv_fs);
            const float C4 = __builtin_amdgcn_cosf((float)k4 * inv_fs);
            const float S4 = __builtin_amdgcn_sinf((float)k4 * inv_fs);
            cB[g] = fmaf(cA[g], C4, -(sA[g] * S4));            // phasor at +4*BLK
            sB[g] = fmaf(sA[g], C4,  (cA[g] * S4));
            C8[g] = __builtin_amdgcn_cosf((float)k8 * inv_fs); // rotation stride 8*BLK
            S8[g] = __builtin_amdgcn_sinf((float)k8 * inv_fs);
            c1[g] = __builtin_amdgcn_cosf((float)kf * inv_fs); // twiddle R^1
            s1[g] = __builtin_amdgcn_sinf((float)kf * inv_fs);
            a0r[g] = 0.f; a0i[g] = 0.f; a1r[g] = 0.f; a1i[g] = 0.f;
            a2r[g] = 0.f; a2i[g] = 0.f; a3r[g] = 0.f; a3i[g] = 0.f;
        }

        int b = cs + 4 * tid;
        for (; b + 4 * BLK + 4 <= iend; b += 8 * BLK) {
            float4 xa = *reinterpret_cast<const float4*>(x + b);
            float4 xb = *reinterpret_cast<const float4*>(x + b + 4 * BLK);
            #pragma unroll
            for (int g = 0; g < FPB; ++g) {
                a0r[g] = fmaf(xa.x, cA[g], a0r[g]); a0i[g] = fmaf(xa.x, sA[g], a0i[g]);
                a1r[g] = fmaf(xa.y, cA[g], a1r[g]); a1i[g] = fmaf(xa.y, sA[g], a1i[g]);
                a2r[g] = fmaf(xa.z, cA[g], a2r[g]); a2i[g] = fmaf(xa.z, sA[g], a2i[g]);
                a3r[g] = fmaf(xa.w, cA[g], a3r[g]); a3i[g] = fmaf(xa.w, sA[g], a3i[g]);
                a0r[g] = fmaf(xb.x, cB[g], a0r[g]); a0i[g] = fmaf(xb.x, sB[g], a0i[g]);
                a1r[g] = fmaf(xb.y, cB[g], a1r[g]); a1i[g] = fmaf(xb.y, sB[g], a1i[g]);
                a2r[g] = fmaf(xb.z, cB[g], a2r[g]); a2i[g] = fmaf(xb.z, sB[g], a2i[g]);
                a3r[g] = fmaf(xb.w, cB[g], a3r[g]); a3i[g] = fmaf(xb.w, sB[g], a3i[g]);
                float cn = fmaf(cA[g], C8[g], -(sA[g] * S8[g]));
                float sn = fmaf(sA[g], C8[g],  (cA[g] * S8[g]));
                cA[g] = cn; sA[g] = sn;
                cn = fmaf(cB[g], C8[g], -(sB[g] * S8[g]));
                sn = fmaf(sB[g], C8[g],  (cB[g] * S8[g]));
                cB[g] = cn; sB[g] = sn;
            }
        }
        // guarded tails (<= 1 pass each for A and B positions)
        #pragma unroll
        for (int p = 0; p < 4; ++p) {
            int idx = b + p;
            if (idx < iend) {
                float xv = x[idx];
                #pragma unroll
                for (int g = 0; g < FPB; ++g) {
                    if (p == 0) { a0r[g] = fmaf(xv, cA[g], a0r[g]); a0i[g] = fmaf(xv, sA[g], a0i[g]); }
                    if (p == 1) { a1r[g] = fmaf(xv, cA[g], a1r[g]); a1i[g] = fmaf(xv, sA[g], a1i[g]); }
                    if (p == 2) { a2r[g] = fmaf(xv, cA[g], a2r[g]); a2i[g] = fmaf(xv, sA[g], a2i[g]); }
                    if (p == 3) { a3r[g] = fmaf(xv, cA[g], a3r[g]); a3i[g] = fmaf(xv, sA[g], a3i[g]); }
                }
            }
        }
        #pragma unroll
        for (int p = 0; p < 4; ++p) {
            int idx = b + 4 * BLK + p;
            if (idx < iend) {
                float xv = x[idx];
                #pragma unroll
                for (int g = 0; g < FPB; ++g) {
                    if (p == 0) { a0r[g] = fmaf(xv, cB[g], a0r[g]); a0i[g] = fmaf(xv, sB[g], a0i[g]); }
                    if (p == 1) { a1r[g] = fmaf(xv, cB[g], a1r[g]); a1i[g] = fmaf(xv, sB[g], a1i[g]); }
                    if (p == 2) { a2r[g] = fmaf(xv, cB[g], a2r[g]); a2i[g] = fmaf(xv, sB[g], a2i[g]); }
                    if (p == 3) { a3r[g] = fmaf(xv, cB[g], a3r[g]); a3i[g] = fmaf(xv, sB[g], a3i[g]); }
                }
            }
        }

        // twiddle combine + wave reduce per freq
        #pragma unroll
        for (int g = 0; g < FPB; ++g) {
            const float c2 = fmaf(c1[g], c1[g], -(s1[g] * s1[g]));
            const float s2 = 2.0f * c1[g] * s1[g];
            const float c3 = fmaf(c2, c1[g], -(s2 * s1[g]));
            const float s3 = fmaf(s2, c1[g],  (c2 * s1[g]));
            float arS = a0r[g], aiS = a0i[g];
            arS = fmaf(c1[g], a1r[g], arS); arS = fmaf(-s1[g], a1i[g], arS);
            aiS = fmaf(c1[g], a1i[g], aiS); aiS = fmaf( s1[g], a1r[g], aiS);
            arS = fmaf(c2, a2r[g], arS); arS = fmaf(-s2, a2i[g], arS);
            aiS = fmaf(c2, a2i[g], aiS); aiS = fmaf( s2, a2r[g], aiS);
            arS = fmaf(c3, a3r[g], arS); arS = fmaf(-s3, a3i[g], arS);
            aiS = fmaf(c3, a3i[g], aiS); aiS = fmaf( s3, a3r[g], aiS);
            #pragma unroll
            for (int o = 32; o > 0; o >>= 1) {
                arS += __shfl_down(arS, o, 64);
                aiS += __shfl_down(aiS, o, 64);
            }
            if (lane == 0) { red[g * 8 + wid * 2] = arS; red[g * 8 + wid * 2 + 1] = aiS; }
        }
        __syncthreads();
        if (tid < FPB) {                       // threads 0..3 finalize freqs j0..j0+3
            const int jg = j0 + tid;
            if (jg < F) {
                float r = 0.f, m = 0.f;
                #pragma unroll
                for (int u = 0; u < 4; ++u) {
                    r += red[tid * 8 + u * 2];
                    m += red[tid * 8 + u * 2 + 1];
                }
                re[jg * SPLIT + chunk] = r;
                im[jg * SPLIT + chunk] = m;
            }
        }
        __syncthreads();                       // protect red[] before next iteration
    }
}

// Kernel 2: fold SPLIT partials per freq, psd, band split, loss.
__global__ void __launch_bounds__(BLK) loss_kernel(
    const float* __restrict__ ws,
    const int* __restrict__ p_ftrue,
    const int* __restrict__ p_delta,
    const int* __restrict__ p_fmin,
    const int* __restrict__ p_fmax,
    float* __restrict__ out)
{
    const int ftrue = *p_ftrue;
    const int delta = *p_delta;
    const int fmin  = *p_fmin;
    const int fmax  = *p_fmax;
    int F = fmax - fmin + 1;
    if (F > MAXF) F = MAXF;

    float t1 = 0.0f, t2 = 0.0f;
    for (int j = threadIdx.x; j < F; j += BLK) {
        float r = 0.0f, m = 0.0f;
        #pragma unroll
        for (int u = 0; u < SPLIT; ++u) {
            r += ws[j * SPLIT + u];
            m += ws[MAXF * SPLIT + j * SPLIT + u];
        }
        float psd = r * r + m * m;
        int   fq  = fmin + j;
        bool wanted = (fq >= ftrue - delta) && (fq <= ftrue + delta);
        if (wanted) t1 += psd; else t2 += psd;
    }

    __shared__ float red[8];
    #pragma unroll
    for (int o = 32; o > 0; o >>= 1) {
        t1 += __shfl_down(t1, o, 64);
        t2 += __shfl_down(t2, o, 64);
    }
    const int lane = threadIdx.x & 63;
    const int wid  = threadIdx.x >> 6;
    if (lane == 0) { red[wid * 2] = t1; red[wid * 2 + 1] = t2; }
    __syncthreads();
    if (threadIdx.x == 0) {
        float a = (red[0] + red[2]) + (red[4] + red[6]);
        float b = (red[1] + red[3]) + (red[5] + red[7]);
        out[0] = -10.0f * log10f(a / b);
    }
}

extern "C" void kernel_launch(void* const* d_in, const int* in_sizes, int n_in,
                              void* d_out, int out_size, void* d_ws, size_t ws_size,
                              hipStream_t stream) {
    const float* x       = (const float*)d_in[0];
    const int*   p_ftrue = (const int*)d_in[1];
    const int*   p_fs    = (const int*)d_in[2];
    const int*   p_delta = (const int*)d_in[3];
    const int*   p_fmin  = (const int*)d_in[4];
    const int*   p_fmax  = (const int*)d_in[5];
    float*       out     = (float*)d_out;
    float*       ws      = (float*)d_ws;
    const int N = in_sizes[0];

    // F known only on device; 1024 grid-strided blocks cover ceil(F/4)*16 work items
    // (F=201 -> 816 live blocks ~ 3/CU ~ 12 waves/CU).
    dft_proj_kernel<<<1024, BLK, 0, stream>>>(x, N, p_fs, p_fmin, p_fmax, ws);
    loss_kernel<<<1, BLK, 0, stream>>>(ws, p_ftrue, p_delta, p_fmin, p_fmax, out);
}

// Round 8
// 12.661 us; speedup vs baseline: 1.4933x; 1.1559x over previous
//
#include <hip/hip_runtime.h>
#include <math.h>

#define BLK   256
#define MAXF  256     // max frequency bins supported (F = 201 here)
#define SPLIT 8       // chunks per frequency-group
#define FPB   2       // frequencies per block (shared x reads -> L2 traffic / 2)
// ws layout (floats): [0 .. MAXF*SPLIT) re partials, [MAXF*SPLIT .. 2*MAXF*SPLIT) im = 16 KB

// fast (a mod fs); exact for a < 2^24 (uses: f*4*tid <= 240*1020, f*4*BLK, f itself)
__device__ __forceinline__ unsigned umod_fast(unsigned a, unsigned fs, float inv_fs) {
    unsigned q = (unsigned)((float)a * inv_fs);
    int r = (int)a - (int)(q * fs);
    if (r < 0) r += (int)fs;
    if (r < 0) r += (int)fs;
    if (r >= (int)fs) r -= (int)fs;
    if (r >= (int)fs) r -= (int)fs;
    return (unsigned)r;
}

// Kernel 1: per-(freq-pair, chunk) partial DFT projection, polyphase-4, FPB=2
// freqs per block. Each float4 pair is loaded ONCE and accumulated into both
// frequencies (L2 traffic halved vs 1 freq/block). Same total freq-setup count
// as the 1-freq/SPLIT=4 variant (808 vs 804) but ~6 main-loop trips/thread.
// Exact integer angles at chain heads: k = (f*i) mod fs; rev = k/fs in [0,1)
// feeds v_sin/cos_f32 (revolution-argument HW trans, zero range reduction).
__global__ void __launch_bounds__(BLK) dft_proj_kernel(
    const float* __restrict__ x, int N,
    const int* __restrict__ p_fs,
    const int* __restrict__ p_fmin,
    const int* __restrict__ p_fmax,
    float* __restrict__ ws)
{
    const unsigned fs   = (unsigned)*p_fs;
    const int      fmin = *p_fmin;
    const int      fmax = *p_fmax;
    int F = fmax - fmin + 1;
    if (F > MAXF) F = MAXF;
    const float inv_fs = 1.0f / (float)fs;

    int Nc = (N + SPLIT - 1) / SPLIT;
    Nc = (Nc + 3) & ~3;                        // multiple of 4 -> float4-aligned chunks
    const int ngrp = (F + FPB - 1) / FPB;
    const int W    = ngrp * SPLIT;

    float* re = ws;
    float* im = ws + MAXF * SPLIT;

    __shared__ float red[FPB * 8];             // [g][wave][re,im], 4 waves

    const int tid  = threadIdx.x;
    const int lane = tid & 63;
    const int wid  = tid >> 6;

    for (int w = blockIdx.x; w < W; w += gridDim.x) {
        const int gi    = w >> 3;              // SPLIT == 8
        const int chunk = w & (SPLIT - 1);
        const int j0    = gi * FPB;
        const int cs    = chunk * Nc;
        const int iend  = min(N, cs + Nc);

        float cA[FPB], sA[FPB], cB[FPB], sB[FPB], C8[FPB], S8[FPB];
        float c1[FPB], s1[FPB];
        float a0r[FPB], a0i[FPB], a1r[FPB], a1i[FPB];
        float a2r[FPB], a2i[FPB], a3r[FPB], a3i[FPB];

        #pragma unroll
        for (int g = 0; g < FPB; ++g) {
            int jg = j0 + g; if (jg >= F) jg = F - 1;          // clamp (write-guarded)
            const unsigned f = (unsigned)(fmin + jg);
            // exact integer angles
            const unsigned kb = (unsigned)(((unsigned long long)f * (unsigned)cs) % fs);
            unsigned pt = umod_fast(f * (unsigned)(4 * tid), fs, inv_fs);
            unsigned k0 = kb + pt; if (k0 >= fs) k0 -= fs;
            const unsigned k4 = umod_fast(f * (unsigned)(4 * BLK), fs, inv_fs);
            unsigned k8 = k4 + k4; if (k8 >= fs) k8 -= fs;
            const unsigned kf = umod_fast(f, fs, inv_fs);
            // phasors + rotation constants (8 trans ops per freq)
            cA[g] = __builtin_amdgcn_cosf((float)k0 * inv_fs);
            sA[g] = __builtin_amdgcn_sinf((float)k0 * inv_fs);
            const float C4 = __builtin_amdgcn_cosf((float)k4 * inv_fs);
            const float S4 = __builtin_amdgcn_sinf((float)k4 * inv_fs);
            cB[g] = fmaf(cA[g], C4, -(sA[g] * S4));            // phasor at +4*BLK
            sB[g] = fmaf(sA[g], C4,  (cA[g] * S4));
            C8[g] = __builtin_amdgcn_cosf((float)k8 * inv_fs); // rotation stride 8*BLK
            S8[g] = __builtin_amdgcn_sinf((float)k8 * inv_fs);
            c1[g] = __builtin_amdgcn_cosf((float)kf * inv_fs); // twiddle R^1
            s1[g] = __builtin_amdgcn_sinf((float)kf * inv_fs);
            a0r[g] = 0.f; a0i[g] = 0.f; a1r[g] = 0.f; a1i[g] = 0.f;
            a2r[g] = 0.f; a2i[g] = 0.f; a3r[g] = 0.f; a3i[g] = 0.f;
        }

        int b = cs + 4 * tid;
        for (; b + 4 * BLK + 4 <= iend; b += 8 * BLK) {
            float4 xa = *reinterpret_cast<const float4*>(x + b);
            float4 xb = *reinterpret_cast<const float4*>(x + b + 4 * BLK);
            #pragma unroll
            for (int g = 0; g < FPB; ++g) {
                a0r[g] = fmaf(xa.x, cA[g], a0r[g]); a0i[g] = fmaf(xa.x, sA[g], a0i[g]);
                a1r[g] = fmaf(xa.y, cA[g], a1r[g]); a1i[g] = fmaf(xa.y, sA[g], a1i[g]);
                a2r[g] = fmaf(xa.z, cA[g], a2r[g]); a2i[g] = fmaf(xa.z, sA[g], a2i[g]);
                a3r[g] = fmaf(xa.w, cA[g], a3r[g]); a3i[g] = fmaf(xa.w, sA[g], a3i[g]);
                a0r[g] = fmaf(xb.x, cB[g], a0r[g]); a0i[g] = fmaf(xb.x, sB[g], a0i[g]);
                a1r[g] = fmaf(xb.y, cB[g], a1r[g]); a1i[g] = fmaf(xb.y, sB[g], a1i[g]);
                a2r[g] = fmaf(xb.z, cB[g], a2r[g]); a2i[g] = fmaf(xb.z, sB[g], a2i[g]);
                a3r[g] = fmaf(xb.w, cB[g], a3r[g]); a3i[g] = fmaf(xb.w, sB[g], a3i[g]);
                float cn = fmaf(cA[g], C8[g], -(sA[g] * S8[g]));
                float sn = fmaf(sA[g], C8[g],  (cA[g] * S8[g]));
                cA[g] = cn; sA[g] = sn;
                cn = fmaf(cB[g], C8[g], -(sB[g] * S8[g]));
                sn = fmaf(sB[g], C8[g],  (cB[g] * S8[g]));
                cB[g] = cn; sB[g] = sn;
            }
        }
        // guarded tails (<= 1 pass each for A and B positions)
        #pragma unroll
        for (int p = 0; p < 4; ++p) {
            int idx = b + p;
            if (idx < iend) {
                float xv = x[idx];
                #pragma unroll
                for (int g = 0; g < FPB; ++g) {
                    if (p == 0) { a0r[g] = fmaf(xv, cA[g], a0r[g]); a0i[g] = fmaf(xv, sA[g], a0i[g]); }
                    if (p == 1) { a1r[g] = fmaf(xv, cA[g], a1r[g]); a1i[g] = fmaf(xv, sA[g], a1i[g]); }
                    if (p == 2) { a2r[g] = fmaf(xv, cA[g], a2r[g]); a2i[g] = fmaf(xv, sA[g], a2i[g]); }
                    if (p == 3) { a3r[g] = fmaf(xv, cA[g], a3r[g]); a3i[g] = fmaf(xv, sA[g], a3i[g]); }
                }
            }
        }
        #pragma unroll
        for (int p = 0; p < 4; ++p) {
            int idx = b + 4 * BLK + p;
            if (idx < iend) {
                float xv = x[idx];
                #pragma unroll
                for (int g = 0; g < FPB; ++g) {
                    if (p == 0) { a0r[g] = fmaf(xv, cB[g], a0r[g]); a0i[g] = fmaf(xv, sB[g], a0i[g]); }
                    if (p == 1) { a1r[g] = fmaf(xv, cB[g], a1r[g]); a1i[g] = fmaf(xv, sB[g], a1i[g]); }
                    if (p == 2) { a2r[g] = fmaf(xv, cB[g], a2r[g]); a2i[g] = fmaf(xv, sB[g], a2i[g]); }
                    if (p == 3) { a3r[g] = fmaf(xv, cB[g], a3r[g]); a3i[g] = fmaf(xv, sB[g], a3i[g]); }
                }
            }
        }

        // twiddle combine + wave reduce per freq
        #pragma unroll
        for (int g = 0; g < FPB; ++g) {
            const float c2 = fmaf(c1[g], c1[g], -(s1[g] * s1[g]));
            const float s2 = 2.0f * c1[g] * s1[g];
            const float c3 = fmaf(c2, c1[g], -(s2 * s1[g]));
            const float s3 = fmaf(s2, c1[g],  (c2 * s1[g]));
            float arS = a0r[g], aiS = a0i[g];
            arS = fmaf(c1[g], a1r[g], arS); arS = fmaf(-s1[g], a1i[g], arS);
            aiS = fmaf(c1[g], a1i[g], aiS); aiS = fmaf( s1[g], a1r[g], aiS);
            arS = fmaf(c2, a2r[g], arS); arS = fmaf(-s2, a2i[g], arS);
            aiS = fmaf(c2, a2i[g], aiS); aiS = fmaf( s2, a2r[g], aiS);
            arS = fmaf(c3, a3r[g], arS); arS = fmaf(-s3, a3i[g], arS);
            aiS = fmaf(c3, a3i[g], aiS); aiS = fmaf( s3, a3r[g], aiS);
            #pragma unroll
            for (int o = 32; o > 0; o >>= 1) {
                arS += __shfl_down(arS, o, 64);
                aiS += __shfl_down(aiS, o, 64);
            }
            if (lane == 0) { red[g * 8 + wid * 2] = arS; red[g * 8 + wid * 2 + 1] = aiS; }
        }
        __syncthreads();
        if (tid < FPB) {                       // threads 0..1 finalize freqs j0, j0+1
            const int jg = j0 + tid;
            if (jg < F) {
                float r = 0.f, m = 0.f;
                #pragma unroll
                for (int u = 0; u < 4; ++u) {
                    r += red[tid * 8 + u * 2];
                    m += red[tid * 8 + u * 2 + 1];
                }
                re[jg * SPLIT + chunk] = r;
                im[jg * SPLIT + chunk] = m;
            }
        }
        __syncthreads();                       // protect red[] before next iteration
    }
}

// Kernel 2: fold SPLIT partials per freq, psd, band split, loss.
__global__ void __launch_bounds__(BLK) loss_kernel(
    const float* __restrict__ ws,
    const int* __restrict__ p_ftrue,
    const int* __restrict__ p_delta,
    const int* __restrict__ p_fmin,
    const int* __restrict__ p_fmax,
    float* __restrict__ out)
{
    const int ftrue = *p_ftrue;
    const int delta = *p_delta;
    const int fmin  = *p_fmin;
    const int fmax  = *p_fmax;
    int F = fmax - fmin + 1;
    if (F > MAXF) F = MAXF;

    float t1 = 0.0f, t2 = 0.0f;
    for (int j = threadIdx.x; j < F; j += BLK) {
        float r = 0.0f, m = 0.0f;
        #pragma unroll
        for (int u = 0; u < SPLIT; ++u) {
            r += ws[j * SPLIT + u];
            m += ws[MAXF * SPLIT + j * SPLIT + u];
        }
        float psd = r * r + m * m;
        int   fq  = fmin + j;
        bool wanted = (fq >= ftrue - delta) && (fq <= ftrue + delta);
        if (wanted) t1 += psd; else t2 += psd;
    }

    __shared__ float red[8];
    #pragma unroll
    for (int o = 32; o > 0; o >>= 1) {
        t1 += __shfl_down(t1, o, 64);
        t2 += __shfl_down(t2, o, 64);
    }
    const int lane = threadIdx.x & 63;
    const int wid  = threadIdx.x >> 6;
    if (lane == 0) { red[wid * 2] = t1; red[wid * 2 + 1] = t2; }
    __syncthreads();
    if (threadIdx.x == 0) {
        float a = (red[0] + red[2]) + (red[4] + red[6]);
        float b = (red[1] + red[3]) + (red[5] + red[7]);
        out[0] = -10.0f * log10f(a / b);
    }
}

extern "C" void kernel_launch(void* const* d_in, const int* in_sizes, int n_in,
                              void* d_out, int out_size, void* d_ws, size_t ws_size,
                              hipStream_t stream) {
    const float* x       = (const float*)d_in[0];
    const int*   p_ftrue = (const int*)d_in[1];
    const int*   p_fs    = (const int*)d_in[2];
    const int*   p_delta = (const int*)d_in[3];
    const int*   p_fmin  = (const int*)d_in[4];
    const int*   p_fmax  = (const int*)d_in[5];
    float*       out     = (float*)d_out;
    float*       ws      = (float*)d_ws;
    const int N = in_sizes[0];

    // F known only on device; 1024 grid-strided blocks cover ceil(F/2)*8 work items
    // (F=201 -> 808 live blocks ~ 3/CU ~ 12 waves/CU).
    dft_proj_kernel<<<1024, BLK, 0, stream>>>(x, N, p_fs, p_fmin, p_fmax, ws);
    loss_kernel<<<1, BLK, 0, stream>>>(ws, p_ftrue, p_delta, p_fmin, p_fmax, out);
}

// Round 9
// 12.382 us; speedup vs baseline: 1.5269x; 1.0225x over previous
//
#include <hip/hip_runtime.h>
#include <math.h>

#define BLK   1024         // one block owns one whole frequency (16 waves)
#define MAXF  256          // max frequency bins supported (F = 201 here)
#define NW    (BLK / 64)
#define K2B   256
// ws layout (floats): [0 .. MAXF) re, [MAXF .. 2*MAXF) im

// fast (a mod fs); exact for a < 2^24 (uses: f*4*tid <= 240*4092, f*4096, f)
__device__ __forceinline__ unsigned umod_fast(unsigned a, unsigned fs, float inv_fs) {
    unsigned q = (unsigned)((float)a * inv_fs);
    int r = (int)a - (int)(q * fs);
    if (r < 0) r += (int)fs;
    if (r < 0) r += (int)fs;
    if (r >= (int)fs) r -= (int)fs;
    if (r >= (int)fs) r -= (int)fs;
    return (unsigned)r;
}

// Kernel 1: full-N polyphase-4 DFT projection, one frequency per block.
// Exact integer angles at chain heads: k = (f*i) mod fs; rev = k/fs in [0,1)
// feeds v_sin/cos_f32 (revolution-argument HW trans, zero range reduction).
// Inner loop: 3 VALU ops/element, 2 dwordx4 loads / 8 elements; ~12 rotation
// steps per chain -> drift ~1e-6. Block reduce -> re[j], im[j] (no partials).
__global__ void __launch_bounds__(BLK) dft_proj_kernel(
    const float* __restrict__ x, int N,
    const int* __restrict__ p_fs,
    const int* __restrict__ p_fmin,
    const int* __restrict__ p_fmax,
    float* __restrict__ ws)
{
    const unsigned fs   = (unsigned)*p_fs;
    const int      fmin = *p_fmin;
    const int      fmax = *p_fmax;
    int F = fmax - fmin + 1;
    if (F > MAXF) F = MAXF;
    const float inv_fs = 1.0f / (float)fs;

    float* re = ws;
    float* im = ws + MAXF;

    __shared__ float red[2 * NW];

    const int tid  = threadIdx.x;
    const int lane = tid & 63;
    const int wid  = tid >> 6;

    for (int j = blockIdx.x; j < F; j += gridDim.x) {
        const unsigned f = (unsigned)(fmin + j);

        // --- exact integer angles (all products < 2^24 -> float-exact umod) ---
        const unsigned k0 = umod_fast(f * (unsigned)(4 * tid), fs, inv_fs); // elem 4*tid
        const unsigned k4 = umod_fast(f * (unsigned)(4 * BLK), fs, inv_fs); // stride 4*BLK
        unsigned k8 = k4 + k4; if (k8 >= fs) k8 -= fs;                      // stride 8*BLK
        const unsigned kf = umod_fast(f, fs, inv_fs);                       // stride 1

        // phasors + rotation constants (8 trans ops per thread)
        float cA = __builtin_amdgcn_cosf((float)k0 * inv_fs);
        float sA = __builtin_amdgcn_sinf((float)k0 * inv_fs);
        const float C4 = __builtin_amdgcn_cosf((float)k4 * inv_fs);
        const float S4 = __builtin_amdgcn_sinf((float)k4 * inv_fs);
        float cB = fmaf(cA, C4, -(sA * S4));   // phasor at 4*tid + 4*BLK
        float sB = fmaf(sA, C4,  (cA * S4));
        const float C8 = __builtin_amdgcn_cosf((float)k8 * inv_fs);
        const float S8 = __builtin_amdgcn_sinf((float)k8 * inv_fs);

        // 4 polyphase complex accumulators (phases p=0..3 within each float4)
        float a0r = 0.f, a0i = 0.f, a1r = 0.f, a1i = 0.f;
        float a2r = 0.f, a2i = 0.f, a3r = 0.f, a3i = 0.f;

        int b = 4 * tid;
        for (; b + 4 * BLK + 4 <= N; b += 8 * BLK) {   // ~12 trips
            float4 xa = *reinterpret_cast<const float4*>(x + b);
            float4 xb = *reinterpret_cast<const float4*>(x + b + 4 * BLK);
            a0r = fmaf(xa.x, cA, a0r); a0i = fmaf(xa.x, sA, a0i);
            a1r = fmaf(xa.y, cA, a1r); a1i = fmaf(xa.y, sA, a1i);
            a2r = fmaf(xa.z, cA, a2r); a2i = fmaf(xa.z, sA, a2i);
            a3r = fmaf(xa.w, cA, a3r); a3i = fmaf(xa.w, sA, a3i);
            a0r = fmaf(xb.x, cB, a0r); a0i = fmaf(xb.x, sB, a0i);
            a1r = fmaf(xb.y, cB, a1r); a1i = fmaf(xb.y, sB, a1i);
            a2r = fmaf(xb.z, cB, a2r); a2i = fmaf(xb.z, sB, a2i);
            a3r = fmaf(xb.w, cB, a3r); a3i = fmaf(xb.w, sB, a3i);
            float cn = fmaf(cA, C8, -(sA * S8));
            float sn = fmaf(sA, C8,  (cA * S8));
            cA = cn; sA = sn;
            cn = fmaf(cB, C8, -(sB * S8));
            sn = fmaf(sB, C8,  (cB * S8));
            cB = cn; sB = sn;
        }
        #pragma unroll
        for (int p = 0; p < 4; ++p) {                  // guarded tail, A position
            int idx = b + p;
            if (idx < N) {
                float xv = x[idx];
                if (p == 0) { a0r = fmaf(xv, cA, a0r); a0i = fmaf(xv, sA, a0i); }
                if (p == 1) { a1r = fmaf(xv, cA, a1r); a1i = fmaf(xv, sA, a1i); }
                if (p == 2) { a2r = fmaf(xv, cA, a2r); a2i = fmaf(xv, sA, a2i); }
                if (p == 3) { a3r = fmaf(xv, cA, a3r); a3i = fmaf(xv, sA, a3i); }
            }
        }
        #pragma unroll
        for (int p = 0; p < 4; ++p) {                  // guarded tail, B position
            int idx = b + 4 * BLK + p;
            if (idx < N) {
                float xv = x[idx];
                if (p == 0) { a0r = fmaf(xv, cB, a0r); a0i = fmaf(xv, sB, a0i); }
                if (p == 1) { a1r = fmaf(xv, cB, a1r); a1i = fmaf(xv, sB, a1i); }
                if (p == 2) { a2r = fmaf(xv, cB, a2r); a2i = fmaf(xv, sB, a2i); }
                if (p == 3) { a3r = fmaf(xv, cB, a3r); a3i = fmaf(xv, sB, a3i); }
            }
        }

        // twiddle combine: sum = A0 + R A1 + R^2 A2 + R^3 A3, R = e^{i 2pi f/fs}
        const float c1 = __builtin_amdgcn_cosf((float)kf * inv_fs);
        const float s1 = __builtin_amdgcn_sinf((float)kf * inv_fs);
        const float c2 = fmaf(c1, c1, -(s1 * s1));
        const float s2 = 2.0f * c1 * s1;
        const float c3 = fmaf(c2, c1, -(s2 * s1));
        const float s3 = fmaf(s2, c1,  (c2 * s1));
        float arS = a0r, aiS = a0i;
        arS = fmaf(c1, a1r, arS); arS = fmaf(-s1, a1i, arS);
        aiS = fmaf(c1, a1i, aiS); aiS = fmaf( s1, a1r, aiS);
        arS = fmaf(c2, a2r, arS); arS = fmaf(-s2, a2i, arS);
        aiS = fmaf(c2, a2i, aiS); aiS = fmaf( s2, a2r, aiS);
        arS = fmaf(c3, a3r, arS); arS = fmaf(-s3, a3i, arS);
        aiS = fmaf(c3, a3i, aiS); aiS = fmaf( s3, a3r, aiS);

        // wave butterfly + block reduce (16 waves)
        #pragma unroll
        for (int o = 32; o > 0; o >>= 1) {
            arS += __shfl_down(arS, o, 64);
            aiS += __shfl_down(aiS, o, 64);
        }
        if (lane == 0) { red[wid * 2] = arS; red[wid * 2 + 1] = aiS; }
        __syncthreads();
        if (tid == 0) {
            float r = 0.f, m = 0.f;
            #pragma unroll
            for (int u = 0; u < NW; ++u) { r += red[u * 2]; m += red[u * 2 + 1]; }
            re[j] = r;
            im[j] = m;
        }
        __syncthreads();   // protect red[] (only if grid-strided, F > gridDim)
    }
}

// Kernel 2: psd = re^2 + im^2 per freq, band split, loss. 402 contiguous reads.
__global__ void __launch_bounds__(K2B) loss_kernel(
    const float* __restrict__ ws,
    const int* __restrict__ p_ftrue,
    const int* __restrict__ p_delta,
    const int* __restrict__ p_fmin,
    const int* __restrict__ p_fmax,
    float* __restrict__ out)
{
    const int ftrue = *p_ftrue;
    const int delta = *p_delta;
    const int fmin  = *p_fmin;
    const int fmax  = *p_fmax;
    int F = fmax - fmin + 1;
    if (F > MAXF) F = MAXF;

    float t1 = 0.0f, t2 = 0.0f;
    for (int j = threadIdx.x; j < F; j += K2B) {
        float r   = ws[j];
        float m   = ws[MAXF + j];
        float psd = r * r + m * m;
        int   fq  = fmin + j;
        bool wanted = (fq >= ftrue - delta) && (fq <= ftrue + delta);
        if (wanted) t1 += psd; else t2 += psd;
    }

    __shared__ float red[8];
    #pragma unroll
    for (int o = 32; o > 0; o >>= 1) {
        t1 += __shfl_down(t1, o, 64);
        t2 += __shfl_down(t2, o, 64);
    }
    const int lane = threadIdx.x & 63;
    const int wid  = threadIdx.x >> 6;
    if (lane == 0) { red[wid * 2] = t1; red[wid * 2 + 1] = t2; }
    __syncthreads();
    if (threadIdx.x == 0) {
        float a = (red[0] + red[2]) + (red[4] + red[6]);
        float b = (red[1] + red[3]) + (red[5] + red[7]);
        out[0] = -10.0f * log10f(a / b);
    }
}

extern "C" void kernel_launch(void* const* d_in, const int* in_sizes, int n_in,
                              void* d_out, int out_size, void* d_ws, size_t ws_size,
                              hipStream_t stream) {
    const float* x       = (const float*)d_in[0];
    const int*   p_ftrue = (const int*)d_in[1];
    const int*   p_fs    = (const int*)d_in[2];
    const int*   p_delta = (const int*)d_in[3];
    const int*   p_fmin  = (const int*)d_in[4];
    const int*   p_fmax  = (const int*)d_in[5];
    float*       out     = (float*)d_out;
    float*       ws      = (float*)d_ws;
    const int N = in_sizes[0];

    // F known only on device; 256 blocks of 1024 cover F <= MAXF
    // (F=201 -> 201 active blocks, 16 waves each, ~1 block/CU).
    dft_proj_kernel<<<256, BLK, 0, stream>>>(x, N, p_fs, p_fmin, p_fmax, ws);
    loss_kernel<<<1, K2B, 0, stream>>>(ws, p_ftrue, p_delta, p_fmin, p_fmax, out);
}